// Round 7
// baseline (256.028 us; speedup 1.0000x reference)
//
#include <hip/hip_runtime.h>

#define ITERS 20
#define EPS 1e-9f

typedef _Float16 v2h __attribute__((ext_vector_type(2)));

// One wave (64 lanes) per 64x64 matrix. Lane (bi,bj) owns the 8x8 sub-block
// rows [8bi,8bi+8), cols [8bj,8bj+8). E = exp(x) is stored in f16 PAIRS
// (32 VGPRs/lane instead of 64) -> register pressure ~70 -> ~6-7 waves/SIMD.
//
// Matvecs use CDNA mixed-precision ops at FULL f32 rate with f32 accumulate:
//   row:  v_dot2_f32_f16  (2 MACs / 2-cy instr -> row matvec cycles halved)
//   col:  v_fma_mix_f32   (f16 E half via op_sel x f32 u + f32 acc)
// u,v masters stay f32; v converted to f16 pairs once per iter (RTNE casts).
// Cross-lane reduces all on the VALU pipe (fused DPP + permlane16/32_swap).
// Scale updates u = rcp(p+eps) (== reference update up to O(eps)).
// No LDS, no barriers.

template <int CTRL>
__device__ __forceinline__ float dpp_add(float x) {
    int yi = __builtin_amdgcn_update_dpp(0, __float_as_int(x), CTRL, 0xf, 0xf, true);
    return x + __int_as_float(yi);
}

#if __has_builtin(__builtin_amdgcn_permlane16_swap)
// identical inputs: r0+r1 == xor16 butterfly all-reduce, pure VALU
__device__ __forceinline__ float xadd16(float x) {
    unsigned u = __float_as_uint(x);
    auto r = __builtin_amdgcn_permlane16_swap(u, u, false, false);
    return __uint_as_float(r[0]) + __uint_as_float(r[1]);
}
#else
__device__ __forceinline__ float xadd16(float x) {
    return x + __int_as_float(__builtin_amdgcn_ds_swizzle(__float_as_int(x), 0x401F));
}
#endif

#if __has_builtin(__builtin_amdgcn_permlane32_swap)
__device__ __forceinline__ float xadd32(float x) {
    unsigned u = __float_as_uint(x);
    auto r = __builtin_amdgcn_permlane32_swap(u, u, false, false);
    return __uint_as_float(r[0]) + __uint_as_float(r[1]);
}
#else
__device__ __forceinline__ float xadd32(float x) {
    return x + __shfl_xor(x, 32, 64);
}
#endif

// f16x2 dot product with f32 accumulate, full-rate
__device__ __forceinline__ float dot2(v2h a, v2h b, float c) {
#if __has_builtin(__builtin_amdgcn_fdot2)
    return __builtin_amdgcn_fdot2(a, b, c, false);
#else
    float d;
    asm("v_dot2_f32_f16 %0, %1, %2, %3" : "=v"(d) : "v"(a), "v"(b), "v"(c));
    return d;
#endif
}

// d = (f16 lo/hi of a) * b + c, all math f32, full-rate
__device__ __forceinline__ float fma_mix_lo(v2h a, float b, float c) {
    float d;
    asm("v_fma_mix_f32 %0, %1, %2, %3 op_sel:[0,0,0] op_sel_hi:[1,0,0]"
        : "=v"(d) : "v"(a), "v"(b), "v"(c));
    return d;
}
__device__ __forceinline__ float fma_mix_hi(v2h a, float b, float c) {
    float d;
    asm("v_fma_mix_f32 %0, %1, %2, %3 op_sel:[1,0,0] op_sel_hi:[1,0,0]"
        : "=v"(d) : "v"(a), "v"(b), "v"(c));
    return d;
}

__global__ __launch_bounds__(256, 4) void sinkhorn_kernel(
        const float* __restrict__ x, float* __restrict__ out, int nmat) {
    const int lane = threadIdx.x & 63;
    const int wave = threadIdx.x >> 6;
    const int mat  = blockIdx.x * 4 + wave;
    if (mat >= nmat) return;
    const int bi = lane >> 3;   // block-row 0..7 (lane bits 3-5)
    const int bj = lane & 7;    // block-col 0..7 (lane bits 0-2)

    const float4* __restrict__ xin = (const float4*)(x + (size_t)mat * 4096);

    // Load 8x8 block, exp in f32, store as f16 pairs (RTNE casts).
    v2h eh[8][4];
    #pragma unroll
    for (int r = 0; r < 8; ++r) {
        float4 lo = xin[(8 * bi + r) * 16 + 2 * bj + 0];
        float4 hi = xin[(8 * bi + r) * 16 + 2 * bj + 1];
        eh[r][0] = (v2h){(_Float16)__expf(lo.x), (_Float16)__expf(lo.y)};
        eh[r][1] = (v2h){(_Float16)__expf(lo.z), (_Float16)__expf(lo.w)};
        eh[r][2] = (v2h){(_Float16)__expf(hi.x), (_Float16)__expf(hi.y)};
        eh[r][3] = (v2h){(_Float16)__expf(hi.z), (_Float16)__expf(hi.w)};
    }

    float uu[8], vv[8];
    v2h vh[4];
    #pragma unroll
    for (int i = 0; i < 8; ++i) { uu[i] = 1.0f; vv[i] = 1.0f; }
    #pragma unroll
    for (int i = 0; i < 4; ++i) vh[i] = (v2h){(_Float16)1.0f, (_Float16)1.0f};

    for (int it = 0; it < ITERS; ++it) {
        // ---- row phase: p_i = sum_j E[i,j] v_j  (dot2, f32 accumulate) ----
        float p[8];
        #pragma unroll
        for (int r = 0; r < 8; ++r) {
            float s = dot2(eh[r][0], vh[0], 0.0f);
            s = dot2(eh[r][1], vh[1], s);
            s = dot2(eh[r][2], vh[2], s);
            s = dot2(eh[r][3], vh[3], s);
            p[r] = s;
        }
        // all-reduce across the 8 bj lanes (lane bits 0-2) — fused DPP adds
        #pragma unroll
        for (int r = 0; r < 8; ++r) p[r] = dpp_add<0xB1>(p[r]);   // quad_perm xor1
        #pragma unroll
        for (int r = 0; r < 8; ++r) p[r] = dpp_add<0x4E>(p[r]);   // quad_perm xor2
        #pragma unroll
        for (int r = 0; r < 8; ++r) p[r] = dpp_add<0x141>(p[r]);  // row_half_mirror = xor7
        #pragma unroll
        for (int r = 0; r < 8; ++r)
            uu[r] = __builtin_amdgcn_rcpf(p[r] + EPS);

        // ---- col phase: q_j = sum_i E[i,j] u_i  (fma_mix, all f32 math) ----
        float q[8];
        #pragma unroll
        for (int c2 = 0; c2 < 4; ++c2) {
            q[2 * c2 + 0] = fma_mix_lo(eh[0][c2], uu[0], 0.0f);
            q[2 * c2 + 1] = fma_mix_hi(eh[0][c2], uu[0], 0.0f);
        }
        #pragma unroll
        for (int r = 1; r < 8; ++r) {
            #pragma unroll
            for (int c2 = 0; c2 < 4; ++c2) {
                q[2 * c2 + 0] = fma_mix_lo(eh[r][c2], uu[r], q[2 * c2 + 0]);
                q[2 * c2 + 1] = fma_mix_hi(eh[r][c2], uu[r], q[2 * c2 + 1]);
            }
        }
        // all-reduce across the 8 bi lanes (lane bits 3-5) — all VALU
        #pragma unroll
        for (int c = 0; c < 8; ++c) q[c] = dpp_add<0x128>(q[c]);  // row_ror:8 = xor8
        #pragma unroll
        for (int c = 0; c < 8; ++c) q[c] = xadd16(q[c]);          // permlane16_swap
        #pragma unroll
        for (int c = 0; c < 8; ++c) q[c] = xadd32(q[c]);          // permlane32_swap
        #pragma unroll
        for (int c = 0; c < 8; ++c)
            vv[c] = __builtin_amdgcn_rcpf(q[c] + EPS);
        #pragma unroll
        for (int c2 = 0; c2 < 4; ++c2)
            vh[c2] = (v2h){(_Float16)vv[2 * c2], (_Float16)vv[2 * c2 + 1]};
    }

    // ---- epilogue: out = E .* (u v^T), f32 from f16 E via fma_mix ----
    float4* __restrict__ o = (float4*)(out + (size_t)mat * 4096);
    #pragma unroll
    for (int r = 0; r < 8; ++r) {
        float ur = uu[r];
        float uv0 = ur * vv[0], uv1 = ur * vv[1], uv2 = ur * vv[2], uv3 = ur * vv[3];
        float uv4 = ur * vv[4], uv5 = ur * vv[5], uv6 = ur * vv[6], uv7 = ur * vv[7];
        float4 lo, hi;
        lo.x = fma_mix_lo(eh[r][0], uv0, 0.0f);
        lo.y = fma_mix_hi(eh[r][0], uv1, 0.0f);
        lo.z = fma_mix_lo(eh[r][1], uv2, 0.0f);
        lo.w = fma_mix_hi(eh[r][1], uv3, 0.0f);
        hi.x = fma_mix_lo(eh[r][2], uv4, 0.0f);
        hi.y = fma_mix_hi(eh[r][2], uv5, 0.0f);
        hi.z = fma_mix_lo(eh[r][3], uv6, 0.0f);
        hi.w = fma_mix_hi(eh[r][3], uv7, 0.0f);
        o[(8 * bi + r) * 16 + 2 * bj + 0] = lo;
        o[(8 * bi + r) * 16 + 2 * bj + 1] = hi;
    }
}

extern "C" void kernel_launch(void* const* d_in, const int* in_sizes, int n_in,
                              void* d_out, int out_size, void* d_ws, size_t ws_size,
                              hipStream_t stream) {
    const float* x = (const float*)d_in[0];
    float* out = (float*)d_out;
    const int nmat = in_sizes[0] / 4096;          // 8192 matrices of 64x64
    const int blocks = (nmat + 3) / 4;            // 4 matrices (waves) per block
    sinkhorn_kernel<<<blocks, 256, 0, stream>>>(x, out, nmat);
}